// Round 1
// baseline (2435.071 us; speedup 1.0000x reference)
//
#include <hip/hip_runtime.h>

// Problem geometry (static):
//   x: [4, 64, 256, 256] fp32
//   per head (cls,obj,box,pos,ins): Win[64,64], bin[64], Wh[2,64,64], bh[2,64],
//                                   Wout[od,64], bout[od]
//   od = {81, 2, 4, 64, 128}; out: [4, 279, 256, 256] fp32,
//   channel offsets {0, 81, 83, 87, 151}
constexpr int HWSZ = 256 * 256;   // 65536 spatial positions per image
constexpr int CIN  = 64;
constexpr int OUTC = 279;
constexpr int NPIX = 4 * HWSZ;    // 262144

// One thread per pixel. Per-thread hidden vector lives in an LDS column
// (hbuf[c][t]) so that runtime-indexed writes (h[o] for rolled o-loop) don't
// spill register arrays to scratch; compile-time-indexed snapshots (hr[64])
// feed the fully-unrolled dot products. Each thread touches only its own
// column t -> no __syncthreads needed, and lanes map 2-per-bank (free).
template<int OD>
__global__ __launch_bounds__(256)
void head_kernel(const float* __restrict__ x,
                 const float* __restrict__ Win,  const float* __restrict__ bin,
                 const float* __restrict__ Wh,   const float* __restrict__ bh,
                 const float* __restrict__ Wout, const float* __restrict__ bout,
                 float* __restrict__ out)  // pre-offset by head_channel_off*HWSZ
{
    __shared__ float hbuf[CIN][256];    // 64 KiB

    const int t  = threadIdx.x;
    const int p  = blockIdx.x * 256 + t;
    const int b  = p >> 16;             // p / HWSZ
    const int sp = p & (HWSZ - 1);

    const float* xp = x + ((size_t)b * CIN) * HWSZ + sp;

    // ---- load x (64 coalesced strided loads; all issued before use) ----
    float v[CIN];
#pragma unroll
    for (int c = 0; c < CIN; ++c) v[c] = xp[(size_t)c * HWSZ];

    // ---- in-layer: h = relu(Win @ x + bin) ----
    for (int o = 0; o < CIN; ++o) {
        const float* w = Win + o * CIN;          // uniform row -> s_load
        float a0 = 0.f, a1 = 0.f, a2 = 0.f, a3 = 0.f;
#pragma unroll
        for (int c = 0; c < CIN; c += 4) {
            a0 = fmaf(w[c + 0], v[c + 0], a0);
            a1 = fmaf(w[c + 1], v[c + 1], a1);
            a2 = fmaf(w[c + 2], v[c + 2], a2);
            a3 = fmaf(w[c + 3], v[c + 3], a3);
        }
        float a = (a0 + a1) + (a2 + a3) + bin[o];
        hbuf[o][t] = a > 0.f ? a : 0.f;
    }

    // ---- hidden layers: h = h + relu(Wh[l] @ h + bh[l]) ----
    float hr[CIN];
#pragma unroll 2
    for (int l = 0; l < 2; ++l) {
        const float* Wl = Wh + l * CIN * CIN;
        const float* bl = bh + l * CIN;
#pragma unroll
        for (int c = 0; c < CIN; ++c) hr[c] = hbuf[c][t];   // snapshot
        for (int o = 0; o < CIN; ++o) {
            const float* w = Wl + o * CIN;
            float a0 = 0.f, a1 = 0.f, a2 = 0.f, a3 = 0.f;
#pragma unroll
            for (int c = 0; c < CIN; c += 4) {
                a0 = fmaf(w[c + 0], hr[c + 0], a0);
                a1 = fmaf(w[c + 1], hr[c + 1], a1);
                a2 = fmaf(w[c + 2], hr[c + 2], a2);
                a3 = fmaf(w[c + 3], hr[c + 3], a3);
            }
            float a = (a0 + a1) + (a2 + a3) + bl[o];
            a = a > 0.f ? a : 0.f;
            float hold = hbuf[o][t];             // runtime index -> LDS, fine
            hbuf[o][t] = hold + a;
        }
    }

    // ---- out layer: logits = Wout @ h + bout (no activation) ----
#pragma unroll
    for (int c = 0; c < CIN; ++c) hr[c] = hbuf[c][t];
    float* op = out + ((size_t)b * OUTC) * HWSZ + sp;
    for (int o = 0; o < OD; ++o) {
        const float* w = Wout + o * CIN;
        float a0 = 0.f, a1 = 0.f, a2 = 0.f, a3 = 0.f;
#pragma unroll
        for (int c = 0; c < CIN; c += 4) {
            a0 = fmaf(w[c + 0], hr[c + 0], a0);
            a1 = fmaf(w[c + 1], hr[c + 1], a1);
            a2 = fmaf(w[c + 2], hr[c + 2], a2);
            a3 = fmaf(w[c + 3], hr[c + 3], a3);
        }
        op[(size_t)o * HWSZ] = (a0 + a1) + (a2 + a3) + bout[o];
    }
}

extern "C" void kernel_launch(void* const* d_in, const int* in_sizes, int n_in,
                              void* d_out, int out_size, void* d_ws, size_t ws_size,
                              hipStream_t stream)
{
    const float* x = (const float*)d_in[0];
    float* out = (float*)d_out;

    // inputs per head: Win, bin, Wh, bh, Wout, bout  starting at index 1
    auto A = [&](int i) { return (const float*)d_in[i]; };

    const int grid = NPIX / 256;   // 1024 blocks

    // cls: od=81, ch off 0, inputs 1..6
    head_kernel<81><<<grid, 256, 0, stream>>>(
        x, A(1), A(2), A(3), A(4), A(5), A(6), out + (size_t)0 * HWSZ);
    // obj: od=2, ch off 81, inputs 7..12
    head_kernel<2><<<grid, 256, 0, stream>>>(
        x, A(7), A(8), A(9), A(10), A(11), A(12), out + (size_t)81 * HWSZ);
    // box: od=4, ch off 83, inputs 13..18
    head_kernel<4><<<grid, 256, 0, stream>>>(
        x, A(13), A(14), A(15), A(16), A(17), A(18), out + (size_t)83 * HWSZ);
    // pos: od=64, ch off 87, inputs 19..24
    head_kernel<64><<<grid, 256, 0, stream>>>(
        x, A(19), A(20), A(21), A(22), A(23), A(24), out + (size_t)87 * HWSZ);
    // ins: od=128, ch off 151, inputs 25..30
    head_kernel<128><<<grid, 256, 0, stream>>>(
        x, A(25), A(26), A(27), A(28), A(29), A(30), out + (size_t)151 * HWSZ);
}

// Round 4
// 561.895 us; speedup vs baseline: 4.3337x; 4.3337x over previous
//
#include <hip/hip_runtime.h>

typedef unsigned short u16;
typedef unsigned int   u32;
typedef __attribute__((ext_vector_type(8)))  short bf16x8;
typedef __attribute__((ext_vector_type(16))) float f32x16;

// ---- static problem geometry ----
// x: [4,64,256,256] f32; heads (cls,obj,box,pos,ins): od={81,2,4,64,128},
// out channel offsets {0,81,83,87,151}, out [4,279,256,256] f32.
constexpr int NPIX = 4 * 65536;

__device__ constexpr int OD_[5]   = {81, 2, 4, 64, 128};
__device__ constexpr int NFO_[5]  = {3, 1, 1, 2, 4};      // ceil(od/32)
__device__ constexpr int COFF_[5] = {0, 81, 83, 87, 151};
// frag base per head: per head 3*8 hidden frags + 4*NFO out frags
__device__ constexpr int FB_[5]   = {0, 36, 64, 92, 124}; // total 164 frags

struct PW { const float* w[20]; };           // [head*4 + layer] weight ptrs
struct PB {
    const float* x; float* out; const u16* wf;
    const float* b[20];                      // [head*4 + layer] bias ptrs
};

// split f32 -> (hi bf16, lo bf16), truncation both; hi+lo covers ~16 mantissa bits
__device__ __forceinline__ void f2bf(float v, u16& h, u16& l) {
    u32 bi = __builtin_bit_cast(u32, v);
    u32 bh = bi & 0xffff0000u;
    h = (u16)(bi >> 16);
    float vl = v - __builtin_bit_cast(float, bh);
    l = (u16)(__builtin_bit_cast(u32, vl) >> 16);
}

// ---------------- pre-kernel: weights -> B-fragment order (hi/lo planes) ---
// frag layout in ws: frag*2048B = [hi plane 1024B][lo plane 1024B],
// plane = 64 lanes * 16B; lane l, elem j  <->  B[k = ks*16 + (l>>5)*8 + j][col = nf*32 + (l&31)]
// (same (lane,j)->k map as the A-loader below; any k-permutation error cancels)
__global__ __launch_bounds__(256) void prep_weights(PW wp, u16* wf) {
    int slot = blockIdx.x * 256 + threadIdx.x;
    if (slot >= 164 * 64) return;
    int frag = slot >> 6, lane = slot & 63;
    int fb = 0, seg = 0;
    for (int s = 0; s < 20; ++s) {
        int h = s >> 2, ly = s & 3;
        int cnt = (ly < 3) ? 8 : 4 * NFO_[h];
        if (frag < fb + cnt) { seg = s; break; }
        fb += cnt;
    }
    int h = seg >> 2, ly = seg & 3;
    int lf = frag - fb;
    int nf = lf >> 2, ks = lf & 3;
    int col  = nf * 32 + (lane & 31);
    int ksrc = ks * 16 + (lane >> 5) * 8;
    int rows = (ly < 3) ? 64 : OD_[h];
    const float* W = wp.w[seg];
    float wv[8];
    if (col < rows) {
        const float4* q = reinterpret_cast<const float4*>(W + col * 64 + ksrc);
        float4 a = q[0], c = q[1];
        wv[0]=a.x; wv[1]=a.y; wv[2]=a.z; wv[3]=a.w;
        wv[4]=c.x; wv[5]=c.y; wv[6]=c.z; wv[7]=c.w;
    } else {
#pragma unroll
        for (int j = 0; j < 8; ++j) wv[j] = 0.f;
    }
    bf16x8 vh, vl;
#pragma unroll
    for (int j = 0; j < 8; ++j) {
        u16 hh, ll; f2bf(wv[j], hh, ll);
        vh[j] = (short)hh; vl[j] = (short)ll;
    }
    u16* dst = wf + (size_t)frag * 1024 + lane * 8;
    *(bf16x8*)dst         = vh;
    *(bf16x8*)(dst + 512) = vl;
}

// LDS plane: [32 rows][64 ch] bf16 (4 KiB), XOR-swizzled so the stride-128B
// ds_read_b128 column reads spread across banks (G4 attn fix).
__device__ __forceinline__ u32 swz(int row, int ch) {
    return (u32)((row << 7) + (ch << 1)) ^ (u32)((row & 7) << 4);
}

// one ProjConv layer (N=64): acc = A*W^T via hi/lo split, relu+bias, optional skip,
// write back hi/lo planes. All LDS regions are wave-private; no barriers.
template<bool SKIP>
__device__ __forceinline__ void run_layer(const u16* sh, const u16* sl,
                                          u16* dh, u16* dl,
                                          const u16* wf, int fb,
                                          const float* bias, int l) {
    int arow = l & 31, hb = (l >> 5) * 8;
    bf16x8 Ah[4], Al[4];
#pragma unroll
    for (int ks = 0; ks < 4; ++ks) {
        u32 off = swz(arow, ks * 16 + hb);
        Ah[ks] = *(const bf16x8*)((const char*)sh + off);
        Al[ks] = *(const bf16x8*)((const char*)sl + off);
    }
    bf16x8 Bh[2][4], Bl[2][4];
#pragma unroll
    for (int nf = 0; nf < 2; ++nf)
#pragma unroll
        for (int ks = 0; ks < 4; ++ks) {
            const u16* f = wf + (size_t)(fb + nf * 4 + ks) * 1024 + l * 8;
            Bh[nf][ks] = *(const bf16x8*)f;
            Bl[nf][ks] = *(const bf16x8*)(f + 512);
        }
#pragma unroll
    for (int nf = 0; nf < 2; ++nf) {
        int ch = nf * 32 + (l & 31);
        float bv = bias[ch];
        f32x16 acc;
#pragma unroll
        for (int i = 0; i < 16; ++i) acc[i] = 0.f;
#pragma unroll
        for (int ks = 0; ks < 4; ++ks) {
            acc = __builtin_amdgcn_mfma_f32_32x32x16_bf16(Ah[ks], Bh[nf][ks], acc, 0, 0, 0);
            acc = __builtin_amdgcn_mfma_f32_32x32x16_bf16(Ah[ks], Bl[nf][ks], acc, 0, 0, 0);
            acc = __builtin_amdgcn_mfma_f32_32x32x16_bf16(Al[ks], Bh[nf][ks], acc, 0, 0, 0);
        }
#pragma unroll
        for (int reg = 0; reg < 16; ++reg) {
            int row = (reg & 3) + 8 * (reg >> 2) + 4 * (l >> 5);  // m74/m101 C-map
            float v = acc[reg] + bv;
            v = fmaxf(v, 0.f);
            u32 off = swz(row, ch);
            if (SKIP) {
                u16 oh = *(const u16*)((const char*)dh + off);
                u16 ol = *(const u16*)((const char*)dl + off);
                v += __builtin_bit_cast(float, (u32)oh << 16)
                   + __builtin_bit_cast(float, (u32)ol << 16);
            }
            u16 nh, nl; f2bf(v, nh, nl);
            *(u16*)((char*)dh + off) = nh;
            *(u16*)((char*)dl + off) = nl;
        }
    }
}

__device__ __forceinline__ void run_out(const u16* sh, const u16* sl,
                                        const u16* wf, int fb,
                                        const float* bout, int od, int nfo,
                                        float* out, size_t cb, int l) {
    int arow = l & 31, hb = (l >> 5) * 8;
    bf16x8 Ah[4], Al[4];
#pragma unroll
    for (int ks = 0; ks < 4; ++ks) {
        u32 off = swz(arow, ks * 16 + hb);
        Ah[ks] = *(const bf16x8*)((const char*)sh + off);
        Al[ks] = *(const bf16x8*)((const char*)sl + off);
    }
    for (int nf = 0; nf < nfo; ++nf) {          // runtime bound <= 4
        bf16x8 Bh[4], Bl[4];
#pragma unroll
        for (int ks = 0; ks < 4; ++ks) {
            const u16* f = wf + (size_t)(fb + nf * 4 + ks) * 1024 + l * 8;
            Bh[ks] = *(const bf16x8*)f;
            Bl[ks] = *(const bf16x8*)(f + 512);
        }
        int col = nf * 32 + (l & 31);
        float bv = (col < od) ? bout[col] : 0.f;
        f32x16 acc;
#pragma unroll
        for (int i = 0; i < 16; ++i) acc[i] = 0.f;
#pragma unroll
        for (int ks = 0; ks < 4; ++ks) {
            acc = __builtin_amdgcn_mfma_f32_32x32x16_bf16(Ah[ks], Bh[ks], acc, 0, 0, 0);
            acc = __builtin_amdgcn_mfma_f32_32x32x16_bf16(Ah[ks], Bl[ks], acc, 0, 0, 0);
            acc = __builtin_amdgcn_mfma_f32_32x32x16_bf16(Al[ks], Bh[ks], acc, 0, 0, 0);
        }
        if (col < od) {
            float* op = out + cb + ((size_t)col << 16);
#pragma unroll
            for (int reg = 0; reg < 16; ++reg) {
                int row = (reg & 3) + 8 * (reg >> 2) + 4 * (l >> 5);
                op[row] = acc[reg] + bv;
            }
        }
    }
}

// main: block = 4 waves, each wave owns a 32-pixel strip + 16 KiB of LDS
// (Xhi,Xlo,Hhi,Hlo planes). X staged once, reused by all 5 heads.
__global__ __launch_bounds__(256) void heads_main(PB p) {
    __shared__ u16 lds[4][4][2048];             // 64 KiB -> 2 blocks/CU
    int tid = threadIdx.x;
    int w = tid >> 6, l = tid & 63;
    u16* Xh = lds[w][0]; u16* Xl = lds[w][1];
    u16* Hh = lds[w][2]; u16* Hl = lds[w][3];

    int p0  = blockIdx.x * 128 + w * 32;
    int b   = p0 >> 16, hw0 = p0 & 65535;
    const float* xb = p.x + ((size_t)(b * 64) << 16) + hw0;

    // stage x strip -> hi/lo planes
#pragma unroll
    for (int i = 0; i < 8; ++i) {
        int c  = i * 8 + (l >> 3);
        int pq = (l & 7) * 4;
        float4 v4 = *reinterpret_cast<const float4*>(xb + ((size_t)c << 16) + pq);
        float tmp[4] = {v4.x, v4.y, v4.z, v4.w};
#pragma unroll
        for (int q = 0; q < 4; ++q) {
            int row = pq + q;
            u16 hh, ll; f2bf(tmp[q], hh, ll);
            u32 off = swz(row, c);
            *(u16*)((char*)Xh + off) = hh;
            *(u16*)((char*)Xl + off) = ll;
        }
    }
    asm volatile("" ::: "memory");   // compile-time order; DS pipe is in-order per wave

    for (int h = 0; h < 5; ++h) {
        int fb = FB_[h];
        run_layer<false>(Xh, Xl, Hh, Hl, p.wf, fb,      p.b[4*h],     l);
        asm volatile("" ::: "memory");
        run_layer<true >(Hh, Hl, Hh, Hl, p.wf, fb + 8,  p.b[4*h + 1], l);
        asm volatile("" ::: "memory");
        run_layer<true >(Hh, Hl, Hh, Hl, p.wf, fb + 16, p.b[4*h + 2], l);
        asm volatile("" ::: "memory");
        size_t cb = ((size_t)(b * 279 + COFF_[h]) << 16) + (size_t)hw0;
        run_out(Hh, Hl, p.wf, fb + 24, p.b[4*h + 3], OD_[h], NFO_[h], p.out, cb, l);
        asm volatile("" ::: "memory");
    }
}

extern "C" void kernel_launch(void* const* d_in, const int* in_sizes, int n_in,
                              void* d_out, int out_size, void* d_ws, size_t ws_size,
                              hipStream_t stream)
{
    auto A = [&](int i) { return (const float*)d_in[i]; };
    PW wp; PB pb;
    for (int h = 0; h < 5; ++h) {
        const float* Win  = A(1 + 6*h + 0);
        const float* bin  = A(1 + 6*h + 1);
        const float* Wh   = A(1 + 6*h + 2);
        const float* bh   = A(1 + 6*h + 3);
        const float* Wout = A(1 + 6*h + 4);
        const float* bout = A(1 + 6*h + 5);
        wp.w[4*h+0] = Win;  wp.w[4*h+1] = Wh;  wp.w[4*h+2] = Wh + 4096; wp.w[4*h+3] = Wout;
        pb.b[4*h+0] = bin;  pb.b[4*h+1] = bh;  pb.b[4*h+2] = bh + 64;   pb.b[4*h+3] = bout;
    }
    u16* wf = (u16*)d_ws;                       // needs 164*2048 = 328 KiB
    pb.x = (const float*)d_in[0];
    pb.out = (float*)d_out;
    pb.wf = wf;

    prep_weights<<<41, 256, 0, stream>>>(wp, wf);
    heads_main<<<NPIX / 128, 256, 0, stream>>>(pb);
}

// Round 5
// 560.316 us; speedup vs baseline: 4.3459x; 1.0028x over previous
//
#include <hip/hip_runtime.h>

typedef unsigned short u16;
typedef unsigned int   u32;
typedef __attribute__((ext_vector_type(8)))  short bf16x8;
typedef __attribute__((ext_vector_type(4)))  float f32x4;
typedef __attribute__((ext_vector_type(16))) float f32x16;

// x: [4,64,256,256] f32; heads (cls,obj,box,pos,ins): od={81,2,4,64,128},
// out offsets {0,81,83,87,151}; out [4,279,256,256] f32.
constexpr int NPIX = 4 * 65536;

__device__ constexpr int OD_[5]   = {81, 2, 4, 64, 128};
__device__ constexpr int NFO_[5]  = {3, 1, 1, 2, 4};      // ceil(od/32)
__device__ constexpr int COFF_[5] = {0, 81, 83, 87, 151};
__device__ constexpr int FB_[5]   = {0, 36, 64, 92, 124}; // frag bases, 164 total

struct PW { const float* w[20]; };
struct PB { const float* x; float* out; const u16* wf; const float* b[20]; };

// f32 -> (hi bf16, lo bf16), truncation; hi+lo ~16 mantissa bits
__device__ __forceinline__ void split2(float v, short& hi, short& lo) {
    u32 bi = __builtin_bit_cast(u32, v);
    float lof = v - __builtin_bit_cast(float, bi & 0xffff0000u);
    hi = (short)(bi >> 16);
    lo = (short)(__builtin_bit_cast(u32, lof) >> 16);
}

// ---------------- pre-kernel: weights -> B-fragment order (hi/lo planes) ----
// frag*2048B = [hi 1024B][lo 1024B]; lane l elem j <-> B[k=ks*16+(l>>5)*8+j][col=nf*32+(l&31)]
// (identical (lane,j)->k map as the A-side below; k-permutation errors cancel)
__global__ __launch_bounds__(256) void prep_weights(PW wp, u16* wf) {
    int slot = blockIdx.x * 256 + threadIdx.x;
    if (slot >= 164 * 64) return;
    int frag = slot >> 6, lane = slot & 63;
    int fb = 0, seg = 0;
    for (int s = 0; s < 20; ++s) {
        int h = s >> 2, ly = s & 3;
        int cnt = (ly < 3) ? 8 : 4 * NFO_[h];
        if (frag < fb + cnt) { seg = s; break; }
        fb += cnt;
    }
    int h = seg >> 2, ly = seg & 3;
    int lf = frag - fb;
    int nf = lf >> 2, ks = lf & 3;
    int col  = nf * 32 + (lane & 31);
    int ksrc = ks * 16 + (lane >> 5) * 8;
    int rows = (ly < 3) ? 64 : OD_[h];
    const float* W = wp.w[seg];
    float wv[8];
    if (col < rows) {
        const float4* q = reinterpret_cast<const float4*>(W + col * 64 + ksrc);
        float4 a = q[0], c = q[1];
        wv[0]=a.x; wv[1]=a.y; wv[2]=a.z; wv[3]=a.w;
        wv[4]=c.x; wv[5]=c.y; wv[6]=c.z; wv[7]=c.w;
    } else {
#pragma unroll
        for (int j = 0; j < 8; ++j) wv[j] = 0.f;
    }
    bf16x8 vh, vl;
#pragma unroll
    for (int j = 0; j < 8; ++j) { short a, b; split2(wv[j], a, b); vh[j]=a; vl[j]=b; }
    u16* dst = wf + (size_t)frag * 1024 + lane * 8;
    *(bf16x8*)dst         = vh;
    *(bf16x8*)(dst + 512) = vl;
}

// H plane: [32 rows][64 ch] f32 (8 KiB/wave), XOR swizzle breaks the
// 256B-row-stride 32-way conflict on ds_read_b128 (residual 4-way).
__device__ __forceinline__ u32 hswz(int row, int ch) {
    return (u32)((row << 8) + (ch << 2)) ^ (u32)((row & 7) << 4);
}

// load A-fragments (one ks slice) from H and split into hi/lo bf16
__device__ __forceinline__ void load_a(const char* H, int arow, int ks, int hb,
                                       bf16x8& ah, bf16x8& al) {
    u32 o0 = hswz(arow, ks * 16 + hb);
    f32x4 q0 = *(const f32x4*)(H + o0);
    f32x4 q1 = *(const f32x4*)(H + (o0 ^ 16));
    float qa[8] = {q0.x, q0.y, q0.z, q0.w, q1.x, q1.y, q1.z, q1.w};
#pragma unroll
    for (int j = 0; j < 8; ++j) { short a, b; split2(qa[j], a, b); ah[j]=a; al[j]=b; }
}

// one hidden ProjConv layer: D = A*W^T (3-term hi/lo), +bias, relu, optional
// +skip (exact f32 from H), write H. Wave-private LDS; DS in-order per wave.
template<bool SKIP, bool FROM_LDS>
__device__ __forceinline__ void proj_layer(const bf16x8* Xh, const bf16x8* Xl,
                                           char* H, const u16* wfb,
                                           const float* bias, int l) {
    int hb = (l >> 5) * 8, arow = l & 31, hi4 = (l >> 5) * 4;
    f32x16 acc0, acc1;
#pragma unroll
    for (int i = 0; i < 16; ++i) { acc0[i] = 0.f; acc1[i] = 0.f; }
#pragma unroll
    for (int ks = 0; ks < 4; ++ks) {
        bf16x8 ah, al;
        if (FROM_LDS) load_a(H, arow, ks, hb, ah, al);
        else          { ah = Xh[ks]; al = Xl[ks]; }
        const u16* f0 = wfb + (size_t)ks * 1024;
        const u16* f1 = wfb + (size_t)(4 + ks) * 1024;
        bf16x8 b0h = *(const bf16x8*)f0, b0l = *(const bf16x8*)(f0 + 512);
        bf16x8 b1h = *(const bf16x8*)f1, b1l = *(const bf16x8*)(f1 + 512);
        acc0 = __builtin_amdgcn_mfma_f32_32x32x16_bf16(ah, b0h, acc0, 0, 0, 0);
        acc0 = __builtin_amdgcn_mfma_f32_32x32x16_bf16(ah, b0l, acc0, 0, 0, 0);
        acc0 = __builtin_amdgcn_mfma_f32_32x32x16_bf16(al, b0h, acc0, 0, 0, 0);
        acc1 = __builtin_amdgcn_mfma_f32_32x32x16_bf16(ah, b1h, acc1, 0, 0, 0);
        acc1 = __builtin_amdgcn_mfma_f32_32x32x16_bf16(ah, b1l, acc1, 0, 0, 0);
        acc1 = __builtin_amdgcn_mfma_f32_32x32x16_bf16(al, b1h, acc1, 0, 0, 0);
    }
    auto epi = [&](const f32x16& acc, int nf) {
        int ch = nf * 32 + (l & 31);
        float bv = bias[ch];
#pragma unroll
        for (int reg = 0; reg < 16; ++reg) {
            int row = (reg & 3) + 8 * (reg >> 2) + hi4;   // m74/m101 C-map
            u32 off = hswz(row, ch);
            float v = fmaxf(acc[reg] + bv, 0.f);
            if (SKIP) v += *(const float*)(H + off);
            *(float*)(H + off) = v;
        }
    };
    epi(acc0, 0);
    epi(acc1, 1);
}

// out layer: logits = W h + b, float4 stores (4 consecutive rows per quad)
__device__ __forceinline__ void out_layer(const char* H, const u16* wfb,
                                          const float* bout, int od, int nfo,
                                          float* op_base, int l) {
    int hb = (l >> 5) * 8, arow = l & 31, hi4 = (l >> 5) * 4;
    bf16x8 Ah[4], Al[4];
#pragma unroll
    for (int ks = 0; ks < 4; ++ks) load_a(H, arow, ks, hb, Ah[ks], Al[ks]);
    for (int nf = 0; nf < nfo; ++nf) {
        f32x16 acc;
#pragma unroll
        for (int i = 0; i < 16; ++i) acc[i] = 0.f;
#pragma unroll
        for (int ks = 0; ks < 4; ++ks) {
            const u16* f = wfb + (size_t)(nf * 4 + ks) * 1024;
            bf16x8 bh = *(const bf16x8*)f, bl = *(const bf16x8*)(f + 512);
            acc = __builtin_amdgcn_mfma_f32_32x32x16_bf16(Ah[ks], bh, acc, 0, 0, 0);
            acc = __builtin_amdgcn_mfma_f32_32x32x16_bf16(Ah[ks], bl, acc, 0, 0, 0);
            acc = __builtin_amdgcn_mfma_f32_32x32x16_bf16(Al[ks], bh, acc, 0, 0, 0);
        }
        int col = nf * 32 + (l & 31);
        if (col < od) {
            float bv = bout[col];
            float* op = op_base + ((size_t)col << 16);
#pragma unroll
            for (int g = 0; g < 4; ++g) {
                int r0 = 8 * g + hi4;
                f32x4 st = {acc[4*g+0] + bv, acc[4*g+1] + bv,
                            acc[4*g+2] + bv, acc[4*g+3] + bv};
                *(f32x4*)(op + r0) = st;
            }
        }
    }
}

// main: 4 waves/block, wave owns 32 pixels. X strip pre-split in registers
// (32 VGPR); H = 8 KiB f32 LDS/wave -> 32 KiB/block -> target 4 blocks/CU.
__global__ __launch_bounds__(256, 4) void heads_main(PB p) {
    __shared__ char Hs[4][8192];
    int tid = threadIdx.x, w = tid >> 6, l = tid & 63;
    char* H = Hs[w];
    int p0 = blockIdx.x * 128 + w * 32;
    int b = p0 >> 16, hw0 = p0 & 65535;
    int hb = (l >> 5) * 8;
    const float* xb = p.x + ((size_t)(b * 64) << 16) + hw0 + (l & 31);

    bf16x8 Xh[4], Xl[4];
#pragma unroll
    for (int ks = 0; ks < 4; ++ks)
#pragma unroll
        for (int j = 0; j < 8; ++j) {
            int ch = ks * 16 + hb + j;
            float v = xb[(size_t)ch << 16];
            short a, c; split2(v, a, c);
            Xh[ks][j] = a; Xl[ks][j] = c;
        }

    const u16* wfl = p.wf + l * 8;
    for (int h = 0; h < 5; ++h) {                 // runtime loop: keep I-cache small
        const u16* wfb = wfl + (size_t)FB_[h] * 1024;
        proj_layer<false, false>(Xh, Xl, H, wfb,              p.b[4*h+0], l);
        asm volatile("" ::: "memory");
        proj_layer<true,  true >(Xh, Xl, H, wfb +  8 * 1024,  p.b[4*h+1], l);
        asm volatile("" ::: "memory");
        proj_layer<true,  true >(Xh, Xl, H, wfb + 16 * 1024,  p.b[4*h+2], l);
        asm volatile("" ::: "memory");
        float* op = p.out + ((size_t)(b * 279 + COFF_[h]) << 16) + hw0;
        out_layer(H, wfb + 24 * 1024, p.b[4*h+3], OD_[h], NFO_[h], op, l);
        asm volatile("" ::: "memory");
    }
}

extern "C" void kernel_launch(void* const* d_in, const int* in_sizes, int n_in,
                              void* d_out, int out_size, void* d_ws, size_t ws_size,
                              hipStream_t stream)
{
    auto A = [&](int i) { return (const float*)d_in[i]; };
    PW wp; PB pb;
    for (int h = 0; h < 5; ++h) {
        wp.w[4*h+0] = A(1 + 6*h + 0);           // Win
        wp.w[4*h+1] = A(1 + 6*h + 2);           // Wh[0]
        wp.w[4*h+2] = A(1 + 6*h + 2) + 4096;    // Wh[1]
        wp.w[4*h+3] = A(1 + 6*h + 4);           // Wout
        pb.b[4*h+0] = A(1 + 6*h + 1);           // bin
        pb.b[4*h+1] = A(1 + 6*h + 3);           // bh[0]
        pb.b[4*h+2] = A(1 + 6*h + 3) + 64;      // bh[1]
        pb.b[4*h+3] = A(1 + 6*h + 5);           // bout
    }
    u16* wf = (u16*)d_ws;                       // 164*2048 = 328 KiB
    pb.x = (const float*)d_in[0];
    pb.out = (float*)d_out;
    pb.wf = wf;

    prep_weights<<<41, 256, 0, stream>>>(wp, wf);
    heads_main<<<NPIX / 128, 256, 0, stream>>>(pb);
}